// Round 7
// baseline (526.202 us; speedup 1.0000x reference)
//
#include <hip/hip_runtime.h>
#include <hip/hip_bf16.h>

typedef __attribute__((ext_vector_type(8))) short bf16x8;
typedef __attribute__((ext_vector_type(4))) float f32x4;
typedef unsigned short u16;
typedef unsigned int u32;

#define NP 34                                           // 32 + 2 halo
#define XT_HALF_ELEMS ((size_t)4 * NP * NP * NP * 64)   // 10,061,824 u16
#define XT_HALF_BYTES (4 * NP * NP * NP * 128)          // 20,123,648 B (int-safe)
#define XT_BYTES ((size_t)2 * XT_HALF_ELEMS * 2)        // 40,247,296 B

__device__ __forceinline__ u16 f2bf(float f) {
  __hip_bfloat16 h = __float2bfloat16(f);
  return __builtin_bit_cast(u16, h);
}

__device__ __forceinline__ void gload_lds16(const u16* g, u16* l) {
  __builtin_amdgcn_global_load_lds(
      (const __attribute__((address_space(1))) u32*)g,
      (__attribute__((address_space(3))) u32*)l, 16, 0, 0);
}

#define WAITV(N) asm volatile("s_waitcnt vmcnt(" #N ")" ::: "memory")
#define BAR() do { __builtin_amdgcn_s_barrier(); asm volatile("" ::: "memory"); } while (0)

// ---------------- kernel 1: demod + modulated bf16 weights ----------------
// wmod[h][b][tap][oc][64] = bf16( weight[oc][ic][tap] * y[b][ic] * demod[b][oc] )
__global__ __launch_bounds__(128) void kmodw(const float* __restrict__ w,
                                             const float* __restrict__ y,
                                             u16* __restrict__ wmod) {
  const int oc = blockIdx.x, b = blockIdx.y;
  const int ic = threadIdx.x;               // 128 threads
  const float* wp = w + (oc * 128 + ic) * 27;
  float wv[27];
  float s = 0.f;
#pragma unroll
  for (int t = 0; t < 27; ++t) { wv[t] = wp[t]; s += wv[t] * wv[t]; }
  const float yv = y[b * 128 + ic];
  float v = yv * yv * s;
#pragma unroll
  for (int m = 1; m < 64; m <<= 1) v += __shfl_xor(v, m);
  __shared__ float part[2];
  const int lane = ic & 63, wid = ic >> 6;
  if (lane == 0) part[wid] = v;
  __syncthreads();
  const float demod = rsqrtf(part[0] + part[1] + 1e-8f);
  const float sc = yv * demod;
  const int h = ic >> 6, icr = ic & 63;
#pragma unroll
  for (int t = 0; t < 27; ++t)
    wmod[((size_t)((h * 4 + b) * 27 + t) << 13) + (oc << 6) + icr] =
        f2bf(wv[t] * sc);
}

// ---------------- kernel 2: zero only the halo of xt (both halves) --------
__global__ __launch_bounds__(128) void khalo(u16* __restrict__ xt) {
  const int zy = blockIdx.x, b = blockIdx.y;
  const int zz = zy / NP, yy = zy % NP;
  const int tid = threadIdx.x;
#pragma unroll
  for (int h = 0; h < 2; ++h) {
    u16* row = xt + (size_t)h * XT_HALF_ELEMS +
               ((size_t)((b * NP + zz) * NP + yy) * NP) * 64;
    u32* wp = (u32*)row;                    // 34*64 u16 = 1088 u32
    if (zz == 0 || zz == NP - 1 || yy == 0 || yy == NP - 1) {
#pragma unroll
      for (int i = 0; i < 9; ++i) {
        const int idx = i * 128 + tid;
        if (idx < 1088) wp[idx] = 0;
      }
    } else {
      if (tid < 32) wp[tid] = 0;                       // x = 0 col
      else if (tid < 64) wp[33 * 32 + (tid - 32)] = 0; // x = 33 col
    }
  }
}

// ---------------- kernel 3: f32 -> bf16 transpose-cast (interior) ----------
__global__ __launch_bounds__(256) void kcastx(const float* __restrict__ x,
                                              u16* __restrict__ xt) {
  const int yq = blockIdx.x, z = blockIdx.y, b = blockIdx.z;
  const int tid = threadIdx.x;
  __shared__ u16 t[32 * 132];
  const float* xp = x + (size_t)b * 128 * 32768 + (z * 32 + yq) * 32;
#pragma unroll
  for (int p = 0; p < 16; ++p) {
    const int ic = p * 8 + (tid >> 5), xx = tid & 31;
    t[xx * 132 + ic] = f2bf(xp[(size_t)ic * 32768 + xx]);
  }
  __syncthreads();
#pragma unroll
  for (int p = 0; p < 4; ++p) {
    const int xx = p * 8 + (tid >> 5), ic4 = (tid & 31) << 2;
    const int h = ic4 >> 6, icr = ic4 & 63;
    u16* dst = xt + (size_t)h * XT_HALF_ELEMS +
               ((size_t)(((b * NP + z + 1) * NP + (yq + 1)) * NP + (xx + 1))) * 64 +
               icr;
    *(ushort4*)dst = *(const ushort4*)&t[xx * 132 + ic4];
  }
}

// ---------------- kernel 4: pipelined B-direct conv, 1 barrier/phase ------
// Block: 128 oc x 256 n (8y x 32x) at fixed (b,z). 4 waves, wave tile 128x64.
// 54 phases (h-major, tap-minor). A quad-buffered in LDS, staged 3 ahead.
// af kk0 prefetched 1 phase ahead into regs; kk1 ds_read hides under kk0 MFMA.
// B direct from L2, reg-dbuf'd. Steady WAITV(4); 1 barrier/phase.
__global__ __launch_bounds__(256, 2) void kconv(const u16* __restrict__ xt,
                                                const u16* __restrict__ wmod,
                                                float* __restrict__ out) {
  __shared__ __align__(16) u16 Asm[4][1024 * 8];   // 4 x 16 KiB [oc][64ic]
  const int tid = threadIdx.x;
  const int lane = tid & 63, wn = tid >> 6;        // 4 waves along n
  const int l15 = lane & 15, sg = lane >> 4;
  const int bsw = ((blockIdx.x & 7) << 6) + (blockIdx.x >> 3);  // XCD chunks
  const int yt = bsw & 3, z = (bsw >> 2) & 31, b = bsw >> 7;
  const int y0 = yt << 3;

  const char* xbp = (const char*)xt;

  int bofs[4];
#pragma unroll
  for (int nf = 0; nf < 4; ++nf) {
    const int yy = (wn << 1) + (nf >> 1);
    const int xx = ((nf & 1) << 4) + l15;
    bofs[nf] = b * (NP * NP * NP * 128) +
               ((((z + 1) * NP + (y0 + yy + 1)) * NP + (xx + 1)) << 7) +
               (sg << 4);
  }

  f32x4 acc[8][4];
#pragma unroll
  for (int i = 0; i < 8; ++i)
#pragma unroll
    for (int j = 0; j < 4; ++j) acc[i][j] = (f32x4){0.f, 0.f, 0.f, 0.f};

  auto phB = [&](int p) -> int {
    const int h = p >= 27 ? 1 : 0;
    const int t = p - 27 * h;
    const int dz = t / 9 - 1, dy = (t / 3) % 3 - 1, dx = t % 3 - 1;
    return h * XT_HALF_BYTES + ((dz * NP + dy) * NP + dx) * 128;
  };
  auto loadB = [&](bf16x8* bv, int p) {
    const int toff = phB(p);
#pragma unroll
    for (int nf = 0; nf < 4; ++nf)
#pragma unroll
      for (int kk = 0; kk < 2; ++kk)
        bv[nf * 2 + kk] =
            *(const bf16x8*)(xbp + (size_t)(bofs[nf] + toff + (kk << 6)));
  };
  auto stageA = [&](int p) {                 // -> Asm[p & 3]
    const int h = p >= 27 ? 1 : 0;
    const int t = p - 27 * h;
    const u16* base = wmod + ((size_t)((h * 4 + b) * 27 + t) << 13);
    u16* dst = &Asm[p & 3][0];
#pragma unroll
    for (int k = 0; k < 4; ++k) {
      const int s = (k << 8) + tid;
      const int oc = s >> 3, jp = s & 7, jg = jp ^ (oc & 7);
      gload_lds16(base + (oc << 6) + (jg << 3), dst + (s << 3));
    }
  };
  auto ldAf = [&](bf16x8* af, int par, int kk) {   // 8 ds_read_b128
    const u16* Ah = &Asm[par][0];
#pragma unroll
    for (int m = 0; m < 8; ++m) {
      const int oc = (m << 4) + l15;
      const int jp = ((kk << 2) + sg) ^ (oc & 7);
      af[m] = *(const bf16x8*)&Ah[(oc << 6) + (jp << 3)];
    }
  };

#define COMPUTE(AF0, AF1, BV)                                                \
  {                                                                          \
    __builtin_amdgcn_s_setprio(1);                                           \
    _Pragma("unroll") for (int m = 0; m < 8; ++m)                            \
      _Pragma("unroll") for (int nf = 0; nf < 4; ++nf)                       \
        acc[m][nf] = __builtin_amdgcn_mfma_f32_16x16x32_bf16(                \
            (AF0)[m], (BV)[nf * 2 + 0], acc[m][nf], 0, 0, 0);                \
    _Pragma("unroll") for (int m = 0; m < 8; ++m)                            \
      _Pragma("unroll") for (int nf = 0; nf < 4; ++nf)                       \
        acc[m][nf] = __builtin_amdgcn_mfma_f32_16x16x32_bf16(                \
            (AF1)[m], (BV)[nf * 2 + 1], acc[m][nf], 0, 0, 0);                \
    __builtin_amdgcn_s_setprio(0);                                           \
  }

  bf16x8 afE[8], afO[8], afk1[8], bvE[8], bvO[8];

  // prologue (issue order matters for the vmcnt ledger):
  stageA(0);            // buf0, 4 loads
  stageA(1);            // buf1, 4
  loadB(bvE, 0);        // 8
  stageA(2);            // buf2, 4
  WAITV(16); BAR();     // A(0) published; leaves A1,B0,A2 in flight
  ldAf(afE, 0, 0);      // prefetch af(0) kk0

  for (int q = 0; q < 25; ++q) {
    const int p0 = q << 1;
    // even phase p0 (cur = afE/bvE)
    WAITV(4); BAR();                 // drains A(p0+1), bv(p0); leaves A(p0+2)
    loadB(bvO, p0 + 1);
    stageA(p0 + 3);
    ldAf(afk1, p0 & 3, 1);           // this phase's kk1
    ldAf(afO, (p0 + 1) & 3, 0);      // next phase's kk0
    COMPUTE(afE, afk1, bvE);
    // odd phase p0+1 (cur = afO/bvO)
    WAITV(4); BAR();
    loadB(bvE, p0 + 2);
    stageA(p0 + 4);
    ldAf(afk1, (p0 + 1) & 3, 1);
    ldAf(afE, (p0 + 2) & 3, 0);
    COMPUTE(afO, afk1, bvO);
  }
  // phase 50 (even)
  WAITV(4); BAR();
  loadB(bvO, 51);
  stageA(53);
  ldAf(afk1, 50 & 3, 1);
  ldAf(afO, 51 & 3, 0);
  COMPUTE(afE, afk1, bvE);
  // phase 51 (odd) — no stageA (54 doesn't exist)
  WAITV(4); BAR();
  loadB(bvE, 52);
  ldAf(afk1, 51 & 3, 1);
  ldAf(afE, 52 & 3, 0);
  COMPUTE(afO, afk1, bvO);
  // phase 52 (even) — need A(53)+bv(52) fully drained
  WAITV(0); BAR();
  loadB(bvO, 53);
  ldAf(afk1, 52 & 3, 1);
  ldAf(afO, 53 & 3, 0);
  COMPUTE(afE, afk1, bvE);
  // phase 53 (odd) — final
  WAITV(0); BAR();
  ldAf(afk1, 53 & 3, 1);
  COMPUTE(afO, afk1, bvO);

  // epilogue: C/D col=l15 (n), row=sg*4+r (oc within 16)
#pragma unroll
  for (int m = 0; m < 8; ++m) {
    const int ocb = (m << 4) + (sg << 2);
#pragma unroll
    for (int nf = 0; nf < 4; ++nf) {
      const int n = (wn << 6) + (nf << 4) + l15;
      const int yy = n >> 5, xx = n & 31;
      float* op = out + ((size_t)(b * 128 + ocb) << 15) + (z << 10) +
                  ((y0 + yy) << 5) + xx;
#pragma unroll
      for (int r = 0; r < 4; ++r) op[(size_t)r << 15] = acc[m][nf][r];
    }
  }
#undef COMPUTE
}

extern "C" void kernel_launch(void* const* d_in, const int* in_sizes, int n_in,
                              void* d_out, int out_size, void* d_ws, size_t ws_size,
                              hipStream_t stream) {
  const float* x = (const float*)d_in[0];
  const float* y = (const float*)d_in[1];
  const float* w = (const float*)d_in[2];
  float* out = (float*)d_out;
  u16* xt = (u16*)d_ws;
  u16* wmod = (u16*)((char*)d_ws + XT_BYTES);

  hipLaunchKernelGGL(khalo, dim3(NP * NP, 4), dim3(128), 0, stream, xt);
  hipLaunchKernelGGL(kmodw, dim3(128, 4), dim3(128), 0, stream, w, y, wmod);
  hipLaunchKernelGGL(kcastx, dim3(32, 32, 4), dim3(256), 0, stream, x, xt);
  hipLaunchKernelGGL(kconv, dim3(512), dim3(256), 0, stream, xt, wmod, out);
}

// Round 8
// 153.090 us; speedup vs baseline: 3.4372x; 3.4372x over previous
//
#include <hip/hip_runtime.h>
#include <hip/hip_bf16.h>

typedef __attribute__((ext_vector_type(8))) short bf16x8;
typedef __attribute__((ext_vector_type(16))) float f32x16;
typedef unsigned short u16;
typedef unsigned int u32;

#define NP 34                                           // 32 + 2 halo
#define XT_BYTES ((size_t)4 * NP * NP * NP * 128 * 2)   // 40,247,296 B

__device__ __forceinline__ u16 f2bf(float f) {
  __hip_bfloat16 h = __float2bfloat16(f);
  return __builtin_bit_cast(u16, h);
}

__device__ __forceinline__ void gload_lds16(const u16* g, u16* l) {
  __builtin_amdgcn_global_load_lds(
      (const __attribute__((address_space(1))) u32*)g,
      (__attribute__((address_space(3))) u32*)l, 16, 0, 0);
}

// ---------------- kernel 1: demod + modulated bf16 weights ----------------
// wmod[b][tap][oc][ic] = bf16( weight[oc][ic][tap] * y[b][ic] * demod[b][oc] )
__global__ __launch_bounds__(128) void kmodw(const float* __restrict__ w,
                                             const float* __restrict__ y,
                                             u16* __restrict__ wmod) {
  const int oc = blockIdx.x, b = blockIdx.y;
  const int ic = threadIdx.x;               // 128 threads
  const float* wp = w + (oc * 128 + ic) * 27;
  float wv[27];
  float s = 0.f;
#pragma unroll
  for (int t = 0; t < 27; ++t) { wv[t] = wp[t]; s += wv[t] * wv[t]; }
  const float yv = y[b * 128 + ic];
  float v = yv * yv * s;
#pragma unroll
  for (int m = 1; m < 64; m <<= 1) v += __shfl_xor(v, m);
  __shared__ float part[2];
  const int lane = ic & 63, wid = ic >> 6;
  if (lane == 0) part[wid] = v;
  __syncthreads();
  const float demod = rsqrtf(part[0] + part[1] + 1e-8f);
  const float sc = yv * demod;
#pragma unroll
  for (int t = 0; t < 27; ++t)
    wmod[((b * 27 + t) * 128 + oc) * 128 + ic] = f2bf(wv[t] * sc);
}

// ---------------- kernel 2: zero only the halo of xt ----------------------
__global__ __launch_bounds__(128) void khalo(u16* __restrict__ xt) {
  const int zy = blockIdx.x, b = blockIdx.y;
  const int zz = zy / NP, yy = zy % NP;
  u16* row = xt + ((size_t)((b * NP + zz) * NP + yy) * NP) * 128;
  u32* wp = (u32*)row;                      // 34*128 u16 = 2176 u32
  if (zz == 0 || zz == NP - 1 || yy == 0 || yy == NP - 1) {
#pragma unroll
    for (int i = 0; i < 17; ++i) wp[i * 128 + threadIdx.x] = 0;
  } else {
    if (threadIdx.x < 64) wp[threadIdx.x] = 0;
    else ((u32*)(row + 33 * 128))[threadIdx.x - 64] = 0;
  }
}

// ---------------- kernel 3: f32 -> bf16 transpose-cast (interior) ----------
__global__ __launch_bounds__(256) void kcastx(const float* __restrict__ x,
                                              u16* __restrict__ xt) {
  const int yq = blockIdx.x, z = blockIdx.y, b = blockIdx.z;
  const int tid = threadIdx.x;
  __shared__ u16 t[32 * 132];               // [x][ic], stride 132 kills conflicts
  const float* xp = x + (size_t)b * 128 * 32768 + (z * 32 + yq) * 32;
#pragma unroll
  for (int p = 0; p < 16; ++p) {
    const int ic = p * 8 + (tid >> 5), xx = tid & 31;
    t[xx * 132 + ic] = f2bf(xp[(size_t)ic * 32768 + xx]);
  }
  __syncthreads();
  u16* xtb = xt + (((size_t)(b * NP + z + 1) * NP + (yq + 1)) * NP + 1) * 128;
#pragma unroll
  for (int p = 0; p < 4; ++p) {
    const int xx = p * 8 + (tid >> 5), icq = tid & 31;
    *(ushort4*)(xtb + (size_t)xx * 128 + icq * 4) = *(const ushort4*)&t[xx * 132 + icq * 4];
  }
}

// ---------------- kernel 4: implicit-GEMM conv, 32x32x16 MFMA -------------
// R1's proven 2-barrier structure; only the MFMA shape (and thus fragment
// reads + epilogue) changed. Block: 128 oc x 128 n, 4 waves 2x2, wave tile
// 64x64 = 2x2 MFMA tiles of 32x32, acc = 4 x f32x16 (64 AGPR).
__global__ __launch_bounds__(256, 2) void kconv(const u16* __restrict__ xt,
                                                const u16* __restrict__ wmod,
                                                float* __restrict__ out) {
  __shared__ u16 Alds[16384];   // [oc][ic], XOR-swizzled 16B slots
  __shared__ u16 Blds[16384];   // [n][ic],  XOR-swizzled 16B slots
  const int tid = threadIdx.x;
  const int lane = tid & 63, wid = tid >> 6;
  const int bid = blockIdx.x;
  const int yt = bid & 7;
  const int z = (bid >> 3) & 31;
  const int b = bid >> 8;
  const int y0 = yt << 2;
  const int wm = wid >> 1, wn = wid & 1;    // 2x2 wave grid
  const int l31 = lane & 31, khalf = lane >> 5;

  const u16* xb = xt + (size_t)b * (NP * NP * NP) * 128;
  const u16* wb = wmod + (size_t)b * 27 * 16384;

  f32x16 acc[2][2];
#pragma unroll
  for (int i = 0; i < 2; ++i)
#pragma unroll
    for (int j = 0; j < 2; ++j)
#pragma unroll
      for (int r = 0; r < 16; ++r) acc[i][j][r] = 0.f;

  const int sgrp = tid >> 4;                // 0..15: row sub-index per round
  const int slot = tid & 15;                // 16B slot within 256B row

  for (int tap = 0; tap < 27; ++tap) {
    const int dz = tap / 9 - 1;
    const int dy = (tap / 3) % 3 - 1;
    const int dx = tap % 3 - 1;
    __syncthreads();                        // previous tile fully consumed
    // --- stage A (32 KiB): wmod[b][tap][oc][ic], pre-swizzled source ---
    {
      const u16* at = wb + tap * 16384;
#pragma unroll
      for (int r = 0; r < 8; ++r) {
        const int row = (r << 4) + sgrp;    // oc
        const u16* src = at + row * 128 + ((slot ^ (row & 7)) << 3);
        gload_lds16(src, &Alds[r * 2048 + wid * 512]);
      }
    }
    // --- stage B (32 KiB): xt rows for the 128 spatial positions ---
    {
      const int pz = z + 1 + dz;
#pragma unroll
      for (int r = 0; r < 8; ++r) {
        const int n = (r << 4) + sgrp;      // spatial index yy*32+xx
        const int yy = n >> 5, xx = n & 31;
        const int py = y0 + yy + 1 + dy;
        const int px = xx + 1 + dx;
        const u16* src = xb + ((size_t)(pz * NP + py) * NP + px) * 128 +
                         ((slot ^ (n & 7)) << 3);
        gload_lds16(src, &Blds[r * 2048 + wid * 512]);
      }
    }
    __syncthreads();                        // compiler drains vmcnt before barrier
    // --- K-loop: 8 chunks of 16 ic, 32x32x16 MFMA ---
#pragma unroll
    for (int kc = 0; kc < 8; ++kc) {
      const int jj = (kc << 1) | khalf;     // 16B slot along K (0..15)
      bf16x8 af[2], bv[2];
#pragma unroll
      for (int m = 0; m < 2; ++m) {
        const int row = (wm << 6) + (m << 5) + l31;
        af[m] = *(const bf16x8*)&Alds[(row << 7) + ((jj ^ (row & 7)) << 3)];
      }
#pragma unroll
      for (int n = 0; n < 2; ++n) {
        const int row = (wn << 6) + (n << 5) + l31;
        bv[n] = *(const bf16x8*)&Blds[(row << 7) + ((jj ^ (row & 7)) << 3)];
      }
      __builtin_amdgcn_s_setprio(1);
#pragma unroll
      for (int m = 0; m < 2; ++m)
#pragma unroll
        for (int n = 0; n < 2; ++n)
          acc[m][n] = __builtin_amdgcn_mfma_f32_32x32x16_bf16(af[m], bv[n],
                                                              acc[m][n], 0, 0, 0);
      __builtin_amdgcn_s_setprio(0);
    }
  }
  // --- epilogue: C/D col=lane&31, row=(reg&3)+8*(reg>>2)+4*(lane>>5) ---
  const int rbase = khalf << 2;
#pragma unroll
  for (int m = 0; m < 2; ++m) {
#pragma unroll
    for (int n = 0; n < 2; ++n) {
      const int nn = (wn << 6) + (n << 5) + l31;
      const int yy = nn >> 5, xx = nn & 31;
      const size_t sp = (z << 10) + ((y0 + yy) << 5) + xx;
#pragma unroll
      for (int r = 0; r < 16; ++r) {
        const int oc = (wm << 6) + (m << 5) + (r & 3) + ((r >> 2) << 3) + rbase;
        out[((size_t)(b * 128 + oc) << 15) + sp] = acc[m][n][r];
      }
    }
  }
}

extern "C" void kernel_launch(void* const* d_in, const int* in_sizes, int n_in,
                              void* d_out, int out_size, void* d_ws, size_t ws_size,
                              hipStream_t stream) {
  const float* x = (const float*)d_in[0];
  const float* y = (const float*)d_in[1];
  const float* w = (const float*)d_in[2];
  float* out = (float*)d_out;
  u16* xt = (u16*)d_ws;
  u16* wmod = (u16*)((char*)d_ws + XT_BYTES);

  hipLaunchKernelGGL(khalo, dim3(NP * NP, 4), dim3(128), 0, stream, xt);
  hipLaunchKernelGGL(kmodw, dim3(128, 4), dim3(128), 0, stream, w, y, wmod);
  hipLaunchKernelGGL(kcastx, dim3(32, 32, 4), dim3(256), 0, stream, x, xt);
  hipLaunchKernelGGL(kconv, dim3(1024), dim3(256), 0, stream, xt, wmod, out);
}

// Round 9
// 148.526 us; speedup vs baseline: 3.5428x; 1.0307x over previous
//
#include <hip/hip_runtime.h>
#include <hip/hip_bf16.h>

typedef __attribute__((ext_vector_type(8))) short bf16x8;
typedef __attribute__((ext_vector_type(4))) float f32x4;
typedef unsigned short u16;
typedef unsigned int u32;

#define NP 34                                           // 32 + 2 halo
#define XT_BYTES ((size_t)4 * NP * NP * NP * 128 * 2)   // 40,247,296 B

__device__ __forceinline__ u16 f2bf(float f) {
  __hip_bfloat16 h = __float2bfloat16(f);
  return __builtin_bit_cast(u16, h);
}

__device__ __forceinline__ void gload_lds16(const u16* g, u16* l) {
  __builtin_amdgcn_global_load_lds(
      (const __attribute__((address_space(1))) u32*)g,
      (__attribute__((address_space(3))) u32*)l, 16, 0, 0);
}

// ---------------- kernel 1: demod + modulated bf16 weights ----------------
// wmod[b][tap][oc][ic] = bf16( weight[oc][ic][tap] * y[b][ic] * demod[b][oc] )
__global__ __launch_bounds__(128) void kmodw(const float* __restrict__ w,
                                             const float* __restrict__ y,
                                             u16* __restrict__ wmod) {
  const int oc = blockIdx.x, b = blockIdx.y;
  const int ic = threadIdx.x;               // 128 threads
  const float* wp = w + (oc * 128 + ic) * 27;
  float wv[27];
  float s = 0.f;
#pragma unroll
  for (int t = 0; t < 27; ++t) { wv[t] = wp[t]; s += wv[t] * wv[t]; }
  const float yv = y[b * 128 + ic];
  float v = yv * yv * s;
#pragma unroll
  for (int m = 1; m < 64; m <<= 1) v += __shfl_xor(v, m);
  __shared__ float part[2];
  const int lane = ic & 63, wid = ic >> 6;
  if (lane == 0) part[wid] = v;
  __syncthreads();
  const float demod = rsqrtf(part[0] + part[1] + 1e-8f);
  const float sc = yv * demod;
#pragma unroll
  for (int t = 0; t < 27; ++t)
    wmod[((b * 27 + t) * 128 + oc) * 128 + ic] = f2bf(wv[t] * sc);
}

// ---------------- kernel 2: zero only the halo of xt ----------------------
__global__ __launch_bounds__(128) void khalo(u16* __restrict__ xt) {
  const int zy = blockIdx.x, b = blockIdx.y;
  const int zz = zy / NP, yy = zy % NP;
  u16* row = xt + ((size_t)((b * NP + zz) * NP + yy) * NP) * 128;
  u32* wp = (u32*)row;                      // 34*128 u16 = 2176 u32
  if (zz == 0 || zz == NP - 1 || yy == 0 || yy == NP - 1) {
#pragma unroll
    for (int i = 0; i < 17; ++i) wp[i * 128 + threadIdx.x] = 0;
  } else {
    if (threadIdx.x < 64) wp[threadIdx.x] = 0;
    else ((u32*)(row + 33 * 128))[threadIdx.x - 64] = 0;
  }
}

// ---------------- kernel 3: f32 -> bf16 transpose-cast (interior) ----------
__global__ __launch_bounds__(256) void kcastx(const float* __restrict__ x,
                                              u16* __restrict__ xt) {
  const int yq = blockIdx.x, z = blockIdx.y, b = blockIdx.z;
  const int tid = threadIdx.x;
  __shared__ u16 t[32 * 132];               // [x][ic], stride 132 kills conflicts
  const float* xp = x + (size_t)b * 128 * 32768 + (z * 32 + yq) * 32;
#pragma unroll
  for (int p = 0; p < 16; ++p) {
    const int ic = p * 8 + (tid >> 5), xx = tid & 31;
    t[xx * 132 + ic] = f2bf(xp[(size_t)ic * 32768 + xx]);
  }
  __syncthreads();
  u16* xtb = xt + (((size_t)(b * NP + z + 1) * NP + (yq + 1)) * NP + 1) * 128;
#pragma unroll
  for (int p = 0; p < 4; ++p) {
    const int xx = p * 8 + (tid >> 5), icq = tid & 31;
    *(ushort4*)(xtb + (size_t)xx * 128 + icq * 4) = *(const ushort4*)&t[xx * 132 + icq * 4];
  }
}

// ---------------- kernel 4: 2-phase pipelined implicit-GEMM conv ----------
// T3 minimum recipe: per phase { STAGE(next) ; ds_read+MFMA(cur) ;
// __syncthreads() }. 54 ic-half phases (tap-major, h-minor). A/B half-tiles
// [row][64ic] (128B rows, 8 slots) double-buffered: 4x16KiB, 2 blocks/CU.
// Conflict-free XOR-slot layout (R6-verified A pattern, both-sides swizzle).
// Block: 128 oc x 128 n (4y x 32x), 4 waves 2x2, wave tile 64x64, 16x16x32.
__global__ __launch_bounds__(256, 2) void kconv(const u16* __restrict__ xt,
                                                const u16* __restrict__ wmod,
                                                float* __restrict__ out) {
  __shared__ __align__(16) u16 Alds[2][1024 * 8];  // [h][oc(128)][64ic]
  __shared__ __align__(16) u16 Blds[2][1024 * 8];  // [h][n(128)][64ic]
  const int tid = threadIdx.x;
  const int lane = tid & 63, wid = tid >> 6;
  const int l15 = lane & 15, sg = lane >> 4;
  const int bid = blockIdx.x;
  const int yt = bid & 7;
  const int z = (bid >> 3) & 31;
  const int b = bid >> 8;
  const int y0 = yt << 2;
  const int wm = wid >> 1, wn = wid & 1;    // 2x2 wave grid

  const u16* xb = xt + (size_t)b * (NP * NP * NP) * 128;
  const u16* wb = wmod + (size_t)b * 27 * 16384;

  f32x4 acc[4][4];
#pragma unroll
  for (int i = 0; i < 4; ++i)
#pragma unroll
    for (int j = 0; j < 4; ++j) acc[i][j] = (f32x4){0.f, 0.f, 0.f, 0.f};

  // stage phase p: A-half + B-half into buffers [p&1]; 8 gloads/thread
  auto stagePh = [&](int p) {
    const int tap = p >> 1, h = p & 1;
    const int dz = tap / 9 - 1, dy = (tap / 3) % 3 - 1, dx = tap % 3 - 1;
    u16* Ad = &Alds[h][0];
    u16* Bd = &Blds[h][0];
    const u16* at = wb + tap * 16384 + (h << 6);
#pragma unroll
    for (int k = 0; k < 4; ++k) {
      const int s = (k << 8) + tid;           // 0..1023
      const int oc = s >> 3, jp = s & 7;
      gload_lds16(at + (oc << 7) + ((jp ^ (oc & 7)) << 3), Ad + (s << 3));
    }
    const int pz = z + 1 + dz;
#pragma unroll
    for (int k = 0; k < 4; ++k) {
      const int s = (k << 8) + tid;
      const int n = s >> 3, jp = s & 7;
      const int yy = n >> 5, xx = n & 31;
      gload_lds16(xb + ((size_t)(pz * NP + (y0 + yy + 1 + dy)) * NP +
                        (xx + 1 + dx)) * 128 + (h << 6) + ((jp ^ (n & 7)) << 3),
                  Bd + (s << 3));
    }
  };

  // compute phase p from buffers [p&1]: 16 ds_read_b128 + 32 MFMA per wave
  auto compPh = [&](int h) {
    const u16* Ah = &Alds[h][0];
    const u16* Bh = &Blds[h][0];
#pragma unroll
    for (int kk = 0; kk < 2; ++kk) {
      const int ks = (kk << 2) + sg;          // logical slot along 64-ic row
      bf16x8 af[4], bv[4];
#pragma unroll
      for (int m = 0; m < 4; ++m) {
        const int row = (wm << 6) + (m << 4) + l15;
        af[m] = *(const bf16x8*)&Ah[(row << 6) + ((ks ^ (row & 7)) << 3)];
      }
#pragma unroll
      for (int n = 0; n < 4; ++n) {
        const int row = (wn << 6) + (n << 4) + l15;
        bv[n] = *(const bf16x8*)&Bh[(row << 6) + ((ks ^ (row & 7)) << 3)];
      }
      __builtin_amdgcn_s_setprio(1);
#pragma unroll
      for (int m = 0; m < 4; ++m)
#pragma unroll
        for (int n = 0; n < 4; ++n)
          acc[m][n] = __builtin_amdgcn_mfma_f32_16x16x32_bf16(af[m], bv[n],
                                                              acc[m][n], 0, 0, 0);
      __builtin_amdgcn_s_setprio(0);
    }
  };

  // prologue
  stagePh(0);
  __syncthreads();
  // 54 phases; stage next BEFORE computing current (staging flies under MFMA)
  for (int p = 0; p < 53; ++p) {
    stagePh(p + 1);
    compPh(p & 1);
    __syncthreads();
  }
  compPh(1);                                  // phase 53, no further staging

  // epilogue: C/D col=l15 (n), row=sg*4+r (oc within 16)
#pragma unroll
  for (int m = 0; m < 4; ++m) {
    const int ocb = (wm << 6) + (m << 4) + (sg << 2);
#pragma unroll
    for (int n = 0; n < 4; ++n) {
      const int nn = (wn << 6) + (n << 4) + l15;
      const int yy = nn >> 5, xx = nn & 31;
      float* op = out + ((size_t)(b * 128 + ocb) << 15) + (z << 10) +
                  ((y0 + yy) << 5) + xx;
#pragma unroll
      for (int r = 0; r < 4; ++r) op[(size_t)r << 15] = acc[m][n][r];
    }
  }
}

extern "C" void kernel_launch(void* const* d_in, const int* in_sizes, int n_in,
                              void* d_out, int out_size, void* d_ws, size_t ws_size,
                              hipStream_t stream) {
  const float* x = (const float*)d_in[0];
  const float* y = (const float*)d_in[1];
  const float* w = (const float*)d_in[2];
  float* out = (float*)d_out;
  u16* xt = (u16*)d_ws;
  u16* wmod = (u16*)((char*)d_ws + XT_BYTES);

  hipLaunchKernelGGL(khalo, dim3(NP * NP, 4), dim3(128), 0, stream, xt);
  hipLaunchKernelGGL(kmodw, dim3(128, 4), dim3(128), 0, stream, w, y, wmod);
  hipLaunchKernelGGL(kcastx, dim3(32, 32, 4), dim3(256), 0, stream, x, xt);
  hipLaunchKernelGGL(kconv, dim3(1024), dim3(256), 0, stream, xt, wmod, out);
}

// Round 10
// 145.102 us; speedup vs baseline: 3.6264x; 1.0236x over previous
//
#include <hip/hip_runtime.h>
#include <hip/hip_bf16.h>

typedef __attribute__((ext_vector_type(8))) short bf16x8;
typedef __attribute__((ext_vector_type(4))) float f32x4;
typedef unsigned short u16;
typedef unsigned int u32;

#define NP 34                                           // 32 + 2 halo
#define XT_BYTES ((size_t)4 * NP * NP * NP * 128 * 2)   // 40,247,296 B

__device__ __forceinline__ u16 f2bf(float f) {
  __hip_bfloat16 h = __float2bfloat16(f);
  return __builtin_bit_cast(u16, h);
}

__device__ __forceinline__ void gload_lds16(const u16* g, u16* l) {
  __builtin_amdgcn_global_load_lds(
      (const __attribute__((address_space(1))) u32*)g,
      (__attribute__((address_space(3))) u32*)l, 16, 0, 0);
}

// ---------------- kernel 1: demod + modulated bf16 weights ----------------
// wmod[b][tap][oc][ic] = bf16( weight[oc][ic][tap] * y[b][ic] * demod[b][oc] )
__global__ __launch_bounds__(128) void kmodw(const float* __restrict__ w,
                                             const float* __restrict__ y,
                                             u16* __restrict__ wmod) {
  const int oc = blockIdx.x, b = blockIdx.y;
  const int ic = threadIdx.x;               // 128 threads
  const float* wp = w + (oc * 128 + ic) * 27;
  float wv[27];
  float s = 0.f;
#pragma unroll
  for (int t = 0; t < 27; ++t) { wv[t] = wp[t]; s += wv[t] * wv[t]; }
  const float yv = y[b * 128 + ic];
  float v = yv * yv * s;
#pragma unroll
  for (int m = 1; m < 64; m <<= 1) v += __shfl_xor(v, m);
  __shared__ float part[2];
  const int lane = ic & 63, wid = ic >> 6;
  if (lane == 0) part[wid] = v;
  __syncthreads();
  const float demod = rsqrtf(part[0] + part[1] + 1e-8f);
  const float sc = yv * demod;
#pragma unroll
  for (int t = 0; t < 27; ++t)
    wmod[((b * 27 + t) * 128 + oc) * 128 + ic] = f2bf(wv[t] * sc);
}

// ---------------- kernel 2: zero only the halo of xt ----------------------
__global__ __launch_bounds__(128) void khalo(u16* __restrict__ xt) {
  const int zy = blockIdx.x, b = blockIdx.y;
  const int zz = zy / NP, yy = zy % NP;
  u16* row = xt + ((size_t)((b * NP + zz) * NP + yy) * NP) * 128;
  u32* wp = (u32*)row;                      // 34*128 u16 = 2176 u32
  if (zz == 0 || zz == NP - 1 || yy == 0 || yy == NP - 1) {
#pragma unroll
    for (int i = 0; i < 17; ++i) wp[i * 128 + threadIdx.x] = 0;
  } else {
    if (threadIdx.x < 64) wp[threadIdx.x] = 0;
    else ((u32*)(row + 33 * 128))[threadIdx.x - 64] = 0;
  }
}

// ---------------- kernel 3: f32 -> bf16 transpose-cast (interior) ----------
__global__ __launch_bounds__(256) void kcastx(const float* __restrict__ x,
                                              u16* __restrict__ xt) {
  const int yq = blockIdx.x, z = blockIdx.y, b = blockIdx.z;
  const int tid = threadIdx.x;
  __shared__ u16 t[32 * 132];               // [x][ic], stride 132 kills conflicts
  const float* xp = x + (size_t)b * 128 * 32768 + (z * 32 + yq) * 32;
#pragma unroll
  for (int p = 0; p < 16; ++p) {
    const int ic = p * 8 + (tid >> 5), xx = tid & 31;
    t[xx * 132 + ic] = f2bf(xp[(size_t)ic * 32768 + xx]);
  }
  __syncthreads();
  u16* xtb = xt + (((size_t)(b * NP + z + 1) * NP + (yq + 1)) * NP + 1) * 128;
#pragma unroll
  for (int p = 0; p < 4; ++p) {
    const int xx = p * 8 + (tid >> 5), icq = tid & 31;
    *(ushort4*)(xtb + (size_t)xx * 128 + icq * 4) = *(const ushort4*)&t[xx * 132 + icq * 4];
  }
}

// ---------------- kernel 4: 2-phase pipelined conv, hoisted addrs ---------
// R9 skeleton (identical layouts/swizzle/barriers/bytes). Changes:
// (1) staging addresses = per-thread base + wave-uniform incremental offset
//     (no per-phase divisions); (2) fragment register double-buffer at kk
//     granularity so each MFMA cluster starts operand-ready.
__global__ __launch_bounds__(256, 2) void kconv(const u16* __restrict__ xt,
                                                const u16* __restrict__ wmod,
                                                float* __restrict__ out) {
  __shared__ __align__(16) u16 Alds[2][8192];      // [h][oc(128)][64ic]
  __shared__ __align__(16) u16 Blds[2][8192];      // [h][n(128)][64ic]
  const int tid = threadIdx.x;
  const int lane = tid & 63, wid = tid >> 6;
  const int l15 = lane & 15, sg = lane >> 4;
  const int bid = blockIdx.x;
  const int yt = bid & 7;
  const int z = (bid >> 3) & 31;
  const int b = bid >> 8;
  const int y0 = yt << 2;
  const int wm = wid >> 1, wn = wid & 1;           // 2x2 wave grid

  const u16* xb = xt + (size_t)b * (NP * NP * NP) * 128;
  const u16* wb = wmod + (size_t)b * 27 * 16384;

  // ---- hoisted per-thread staging bases (algebraically == R9's addrs) ----
  const int q8 = tid >> 3, jp = tid & 7;           // row-sub, 16B slot
  const int swz = (jp ^ (q8 & 7)) << 3;            // same for A and B
  const u16* aptr = wb + (q8 << 7) + swz;          // + tap*16384 + (h<<6) + (k<<12)
  const u16* bptr = xb + (((z + 1) * NP + (y0 + 1)) * NP + (q8 + 1)) * 128 + swz;
  const int ldso = tid << 3;                       // LDS u16 offset, + k<<11

  f32x4 acc[4][4];
#pragma unroll
  for (int i = 0; i < 4; ++i)
#pragma unroll
    for (int j = 0; j < 4; ++j) acc[i][j] = (f32x4){0.f, 0.f, 0.f, 0.f};

  // wave-uniform counters for the NEXT phase to stage
  int tap1 = 0, h1 = 0;
  int dx1 = -1, dy1 = -1, dz1 = -1;
  int disp1 = (-NP - 1) * NP - 1;                  // tap 0 = (-1,-1,-1)

  auto stageNext = [&]() {
    const u16* ap = aptr + tap1 * 16384 + (h1 << 6);
    const u16* bp = bptr + disp1 * 128 + (h1 << 6);
    u16* Ad = &Alds[h1][ldso];
    u16* Bd = &Blds[h1][ldso];
#pragma unroll
    for (int k = 0; k < 4; ++k) {
      gload_lds16(ap + (k << 12), Ad + (k << 11));
      gload_lds16(bp + k * (NP * 128), Bd + (k << 11));
    }
  };
  auto advance = [&]() {
    h1 ^= 1;
    if (h1 == 0) {
      ++tap1;
      if (++dx1 == 2) {
        dx1 = -1;
        if (++dy1 == 2) { dy1 = -1; ++dz1; }
      }
      disp1 = (dz1 * NP + dy1) * NP + dx1;
    }
  };
  auto ldFragsKK = [&](bf16x8* af, bf16x8* bv, int h, int kk) {
    const u16* Ah = &Alds[h][0];
    const u16* Bh = &Blds[h][0];
    const int ks = (kk << 2) + sg;
#pragma unroll
    for (int m = 0; m < 4; ++m) {
      const int row = (wm << 6) + (m << 4) + l15;
      af[m] = *(const bf16x8*)&Ah[(row << 6) + ((ks ^ (row & 7)) << 3)];
    }
#pragma unroll
    for (int n = 0; n < 4; ++n) {
      const int row = (wn << 6) + (n << 4) + l15;
      bv[n] = *(const bf16x8*)&Bh[(row << 6) + ((ks ^ (row & 7)) << 3)];
    }
  };
  auto mfmaKK = [&](const bf16x8* af, const bf16x8* bv) {
    __builtin_amdgcn_s_setprio(1);
#pragma unroll
    for (int m = 0; m < 4; ++m)
#pragma unroll
      for (int n = 0; n < 4; ++n)
        acc[m][n] = __builtin_amdgcn_mfma_f32_16x16x32_bf16(af[m], bv[n],
                                                            acc[m][n], 0, 0, 0);
    __builtin_amdgcn_s_setprio(0);
  };

  bf16x8 af0[4], bv0[4], af1[4], bv1[4];

  // prologue: stage phase 0, sync, preload its kk0 fragments
  stageNext(); advance();
  __syncthreads();
  ldFragsKK(af0, bv0, 0, 0);

  for (int p = 0; p < 53; ++p) {
    const int hc = p & 1;
    stageNext(); advance();            // stage phase p+1 into buf[(p+1)&1]
    ldFragsKK(af1, bv1, hc, 1);        // kk1 reads fly under kk0 MFMA
    mfmaKK(af0, bv0);
    mfmaKK(af1, bv1);
    __syncthreads();                   // publishes buf[(p+1)&1]
    ldFragsKK(af0, bv0, (p + 1) & 1, 0);
  }
  // tail phase 53 (buf1), kk0 frags already loaded
  ldFragsKK(af1, bv1, 1, 1);
  mfmaKK(af0, bv0);
  mfmaKK(af1, bv1);

  // epilogue: C/D col=l15 (n), row=sg*4+r (oc within 16)
#pragma unroll
  for (int m = 0; m < 4; ++m) {
    const int ocb = (wm << 6) + (m << 4) + (sg << 2);
#pragma unroll
    for (int n = 0; n < 4; ++n) {
      const int nn = (wn << 6) + (n << 4) + l15;
      const int yy = nn >> 5, xx = nn & 31;
      float* op = out + ((size_t)(b * 128 + ocb) << 15) + (z << 10) +
                  ((y0 + yy) << 5) + xx;
#pragma unroll
      for (int r = 0; r < 4; ++r) op[(size_t)r << 15] = acc[m][n][r];
    }
  }
}

extern "C" void kernel_launch(void* const* d_in, const int* in_sizes, int n_in,
                              void* d_out, int out_size, void* d_ws, size_t ws_size,
                              hipStream_t stream) {
  const float* x = (const float*)d_in[0];
  const float* y = (const float*)d_in[1];
  const float* w = (const float*)d_in[2];
  float* out = (float*)d_out;
  u16* xt = (u16*)d_ws;
  u16* wmod = (u16*)((char*)d_ws + XT_BYTES);

  hipLaunchKernelGGL(khalo, dim3(NP * NP, 4), dim3(128), 0, stream, xt);
  hipLaunchKernelGGL(kmodw, dim3(128, 4), dim3(128), 0, stream, w, y, wmod);
  hipLaunchKernelGGL(kcastx, dim3(32, 32, 4), dim3(256), 0, stream, x, xt);
  hipLaunchKernelGGL(kconv, dim3(1024), dim3(256), 0, stream, xt, wmod, out);
}

// Round 11
// 129.306 us; speedup vs baseline: 4.0694x; 1.1222x over previous
//
#include <hip/hip_runtime.h>
#include <hip/hip_bf16.h>

typedef __attribute__((ext_vector_type(8))) short bf16x8;
typedef __attribute__((ext_vector_type(4))) float f32x4;
typedef unsigned short u16;
typedef unsigned int u32;

#define NP 34                                           // 32 + 2 halo
#define XT_BYTES ((size_t)4 * NP * NP * NP * 128 * 2)   // 40,247,296 B

__device__ __forceinline__ u16 f2bf(float f) {
  __hip_bfloat16 h = __float2bfloat16(f);
  return __builtin_bit_cast(u16, h);
}

__device__ __forceinline__ void gload_lds16(const u16* g, u16* l) {
  __builtin_amdgcn_global_load_lds(
      (const __attribute__((address_space(1))) u32*)g,
      (__attribute__((address_space(3))) u32*)l, 16, 0, 0);
}

#define WAITV(N) asm volatile("s_waitcnt vmcnt(" #N ")" ::: "memory")
#define LGKM0() asm volatile("s_waitcnt lgkmcnt(0)" ::: "memory")
#define BAR() do { __builtin_amdgcn_s_barrier(); asm volatile("" ::: "memory"); } while (0)

// ---------------- kernel 1: demod + modulated bf16 weights ----------------
// wmod[b][tap][oc][ic] = bf16( weight[oc][ic][tap] * y[b][ic] * demod[b][oc] )
__global__ __launch_bounds__(128) void kmodw(const float* __restrict__ w,
                                             const float* __restrict__ y,
                                             u16* __restrict__ wmod) {
  const int oc = blockIdx.x, b = blockIdx.y;
  const int ic = threadIdx.x;               // 128 threads
  const float* wp = w + (oc * 128 + ic) * 27;
  float wv[27];
  float s = 0.f;
#pragma unroll
  for (int t = 0; t < 27; ++t) { wv[t] = wp[t]; s += wv[t] * wv[t]; }
  const float yv = y[b * 128 + ic];
  float v = yv * yv * s;
#pragma unroll
  for (int m = 1; m < 64; m <<= 1) v += __shfl_xor(v, m);
  __shared__ float part[2];
  const int lane = ic & 63, wid = ic >> 6;
  if (lane == 0) part[wid] = v;
  __syncthreads();
  const float demod = rsqrtf(part[0] + part[1] + 1e-8f);
  const float sc = yv * demod;
#pragma unroll
  for (int t = 0; t < 27; ++t)
    wmod[((b * 27 + t) * 128 + oc) * 128 + ic] = f2bf(wv[t] * sc);
}

// ---------------- kernel 2: zero only the halo of xt ----------------------
__global__ __launch_bounds__(128) void khalo(u16* __restrict__ xt) {
  const int zy = blockIdx.x, b = blockIdx.y;
  const int zz = zy / NP, yy = zy % NP;
  u16* row = xt + ((size_t)((b * NP + zz) * NP + yy) * NP) * 128;
  u32* wp = (u32*)row;                      // 34*128 u16 = 2176 u32
  if (zz == 0 || zz == NP - 1 || yy == 0 || yy == NP - 1) {
#pragma unroll
    for (int i = 0; i < 17; ++i) wp[i * 128 + threadIdx.x] = 0;
  } else {
    if (threadIdx.x < 64) wp[threadIdx.x] = 0;
    else ((u32*)(row + 33 * 128))[threadIdx.x - 64] = 0;
  }
}

// ---------------- kernel 3: f32 -> bf16 transpose-cast (interior) ----------
__global__ __launch_bounds__(256) void kcastx(const float* __restrict__ x,
                                              u16* __restrict__ xt) {
  const int yq = blockIdx.x, z = blockIdx.y, b = blockIdx.z;
  const int tid = threadIdx.x;
  __shared__ u16 t[32 * 132];               // [x][ic], stride 132 kills conflicts
  const float* xp = x + (size_t)b * 128 * 32768 + (z * 32 + yq) * 32;
#pragma unroll
  for (int p = 0; p < 16; ++p) {
    const int ic = p * 8 + (tid >> 5), xx = tid & 31;
    t[xx * 132 + ic] = f2bf(xp[(size_t)ic * 32768 + xx]);
  }
  __syncthreads();
  u16* xtb = xt + (((size_t)(b * NP + z + 1) * NP + (yq + 1)) * NP + 1) * 128;
#pragma unroll
  for (int p = 0; p < 4; ++p) {
    const int xx = p * 8 + (tid >> 5), icq = tid & 31;
    *(ushort4*)(xtb + (size_t)xx * 128 + icq * 4) = *(const ushort4*)&t[xx * 132 + icq * 4];
  }
}

// ---------------- kernel 4: m201-style 4-phase/K-step pipelined conv ------
// Block: 128 oc x 512 n (16y x 32x at fixed z). 8 waves, wave tile 128x64
// (m201's shape). 54 K-steps = 6 groups (dz,ic-half) x 9 (dy,dx) taps.
// B: one 18-strip x 34-x plane per group, staged ONCE, taps read via LDS
// offsets (9x reuse). A: 16KB/K-step, tri-buffered, staged 2 K-steps ahead.
// Per phase: 4-8 ds_read + <=1 stage load + BAR + lgkm0 + 16 MFMA + BAR.
// Counted vmcnt: WAITV(2) at K-step ends, WAITV(0) only at 5 group seams.
__global__ __launch_bounds__(512, 2) void kconv(const u16* __restrict__ xt,
                                                const u16* __restrict__ wmod,
                                                float* __restrict__ out) {
  __shared__ __align__(16) u16 Bsm[40960];    // 80 KiB: 18x2176 + clamp pad
  __shared__ __align__(16) u16 Asm[3][8192];  // 3 x 16 KiB [oc 128][64 ic]
  const int tid = threadIdx.x;
  const int lane = tid & 63, wn = tid >> 6;   // 8 waves along n
  const int l15 = lane & 15, sgq = lane >> 4;
  const int bid = blockIdx.x;
  const int wgid = ((bid & 7) << 5) + (bid >> 3);   // XCD: all-z per (b,yt)
  const int b = wgid >> 6, yt = (wgid >> 5) & 1, z = wgid & 31;
  const int y0 = yt << 4;

  const u16* xb = xt + (size_t)b * (NP * NP * NP) * 128;
  const u16* wb = wmod + (size_t)b * 27 * 16384;

  f32x4 acc[8][4];
#pragma unroll
  for (int i = 0; i < 8; ++i)
#pragma unroll
    for (int j = 0; j < 4; ++j) acc[i][j] = (f32x4){0.f, 0.f, 0.f, 0.f};

  // A staging per-thread source base (1024 slots, 2 loads/thread)
  const int aoc = tid >> 3, aj = tid & 7;
  const u16* asrc = wb + (aoc << 7) + ((aj ^ (aoc & 7)) << 3);
  const int adst = tid << 3;                  // u16; +4096 for k=1

  // B fragment per-lane bases
  int sybase[4], xp0[4];
#pragma unroll
  for (int nf = 0; nf < 4; ++nf) {
    sybase[nf] = (((wn << 1) + (nf >> 1)) + 1) * 2176;
    xp0[nf] = ((nf & 1) << 4) + l15 + 1;
  }
  const int kswz0 = sgq ^ (l15 & 7);

  auto stageA1 = [&](int ks2, int k) {        // one load of A(ks2)
    const int g2 = ks2 / 9, j2 = ks2 - g2 * 9;
    const int tap = (g2 >> 1) * 9 + j2, hh = g2 & 1;
    gload_lds16(asrc + tap * 16384 + (hh << 6) + (k << 13),
                &Asm[ks2 % 3][adst + (k << 12)]);
  };
  auto stageB = [&](int g) {                  // 10 loads/thread, linear dest
    const int dz = (g >> 1) - 1, hh = g & 1;
    const int zrow = (z + 1 + dz) * NP + y0;
#pragma unroll
    for (int r = 0; r < 10; ++r) {
      int s = r * 512 + tid;
      const int dst = s << 3;                 // UNCLAMPED (pad absorbs tail)
      s = s < 4896 ? s : 4895;
      const int sy = s / 272;
      const int rem = s - sy * 272;
      const int xpos = rem >> 3, j = rem & 7;
      gload_lds16(xb + (size_t)((zrow + sy) * NP + xpos) * 128 + (hh << 6) +
                      ((j ^ (xpos & 7)) << 3),
                  &Bsm[dst]);
    }
  };
  auto ldAf = [&](bf16x8* af, int par, int mh, int kswz) {
    const u16* Ah = &Asm[par][0];
#pragma unroll
    for (int mm = 0; mm < 4; ++mm) {
      const int oc = (mh << 6) + (mm << 4) + l15;
      af[mm] = *(const bf16x8*)&Ah[(oc << 6) + (kswz << 3)];
    }
  };
  auto ldBv = [&](bf16x8* bv, int kk, int dy, int dx) {
#pragma unroll
    for (int nf = 0; nf < 4; ++nf) {
      const int xp = xp0[nf] + dx;
      const int off = sybase[nf] + dy * 2176 + (xp << 6) +
                      ((((kk << 2) + sgq) ^ (xp & 7)) << 3);
      bv[nf] = *(const bf16x8*)&Bsm[off];
    }
  };

  bf16x8 af[4], bv[4];

#define MFMA16(MH)                                                         \
  { __builtin_amdgcn_s_setprio(1);                                         \
    _Pragma("unroll") for (int mm = 0; mm < 4; ++mm)                       \
      _Pragma("unroll") for (int nf = 0; nf < 4; ++nf)                     \
        acc[(MH) * 4 + mm][nf] = __builtin_amdgcn_mfma_f32_16x16x32_bf16(  \
            af[mm], bv[nf], acc[(MH) * 4 + mm][nf], 0, 0, 0);              \
    __builtin_amdgcn_s_setprio(0); }

  // prologue: B(group0) + A(0) + A(1), full drain once
  stageB(0);
  stageA1(0, 0); stageA1(0, 1);
  stageA1(1, 0); stageA1(1, 1);
  WAITV(0); BAR();

  for (int g = 0; g < 6; ++g) {
    for (int j = 0; j < 9; ++j) {
      const int ks = g * 9 + j;
      const int par = ks % 3;
      const int dy = j / 3 - 1, dx = (j % 3) - 1;
      const int ks2 = (ks + 2 <= 53) ? ks + 2 : 53;
      // q0: mh0/kk0 — 8 ds_read + A-prefetch load 0
      ldAf(af, par, 0, kswz0);
      ldBv(bv, 0, dy, dx);
      stageA1(ks2, 0);
      BAR(); LGKM0();
      MFMA16(0);
      BAR();
      // q1: mh1/kk0 — 4 ds_read (bv reused) + A-prefetch load 1
      ldAf(af, par, 1, kswz0);
      stageA1(ks2, 1);
      BAR(); LGKM0();
      MFMA16(1);
      BAR();
      // q2: mh0/kk1 — 8 ds_read
      ldAf(af, par, 0, kswz0 ^ 4);
      ldBv(bv, 1, dy, dx);
      BAR(); LGKM0();
      MFMA16(0);
      BAR();
      // q3: mh1/kk1 — 4 ds_read, then K-step checkpoint
      ldAf(af, par, 1, kswz0 ^ 4);
      BAR(); LGKM0();
      MFMA16(1);
      if (j < 8) {
        WAITV(2); BAR();            // drains A(ks+1); leaves A(ks+2) in flight
      } else {
        BAR();
        if (g < 5) { stageB(g + 1); WAITV(0); BAR(); }   // group seam
      }
    }
  }

  // epilogue: C/D col=l15 (n), row=sgq*4+r (oc within 16)
#pragma unroll
  for (int m = 0; m < 8; ++m) {
    const int ocb = (m << 4) + (sgq << 2);
#pragma unroll
    for (int nf = 0; nf < 4; ++nf) {
      const int n = (wn << 6) + (nf << 4) + l15;
      const int yy = n >> 5, xx = n & 31;
      float* op = out + ((size_t)(b * 128 + ocb) << 15) + (z << 10) +
                  ((y0 + yy) << 5) + xx;
#pragma unroll
      for (int r = 0; r < 4; ++r) op[(size_t)r << 15] = acc[m][nf][r];
    }
  }
#undef MFMA16
}

extern "C" void kernel_launch(void* const* d_in, const int* in_sizes, int n_in,
                              void* d_out, int out_size, void* d_ws, size_t ws_size,
                              hipStream_t stream) {
  const float* x = (const float*)d_in[0];
  const float* y = (const float*)d_in[1];
  const float* w = (const float*)d_in[2];
  float* out = (float*)d_out;
  u16* xt = (u16*)d_ws;
  u16* wmod = (u16*)((char*)d_ws + XT_BYTES);

  hipLaunchKernelGGL(khalo, dim3(NP * NP, 4), dim3(128), 0, stream, xt);
  hipLaunchKernelGGL(kmodw, dim3(128, 4), dim3(128), 0, stream, w, y, wmod);
  hipLaunchKernelGGL(kcastx, dim3(32, 32, 4), dim3(256), 0, stream, x, xt);
  hipLaunchKernelGGL(kconv, dim3(256), dim3(512), 0, stream, xt, wmod, out);
}

// Round 12
// 122.787 us; speedup vs baseline: 4.2855x; 1.0531x over previous
//
#include <hip/hip_runtime.h>
#include <hip/hip_bf16.h>

typedef __attribute__((ext_vector_type(8))) short bf16x8;
typedef __attribute__((ext_vector_type(4))) float f32x4;
typedef unsigned short u16;
typedef unsigned int u32;

#define NP 34                                           // 32 + 2 halo
#define XT_BYTES ((size_t)4 * NP * NP * NP * 128 * 2)   // 40,247,296 B

__device__ __forceinline__ u16 f2bf(float f) {
  __hip_bfloat16 h = __float2bfloat16(f);
  return __builtin_bit_cast(u16, h);
}

__device__ __forceinline__ void gload_lds16(const u16* g, u16* l) {
  __builtin_amdgcn_global_load_lds(
      (const __attribute__((address_space(1))) u32*)g,
      (__attribute__((address_space(3))) u32*)l, 16, 0, 0);
}

#define WAITV(N) asm volatile("s_waitcnt vmcnt(" #N ")" ::: "memory")
#define BAR() do { __builtin_amdgcn_s_barrier(); asm volatile("" ::: "memory"); } while (0)

// ---------------- kernel 1: demod + modulated bf16 weights ----------------
// wmod[b][tap][oc][ic] = bf16( weight[oc][ic][tap] * y[b][ic] * demod[b][oc] )
__global__ __launch_bounds__(128) void kmodw(const float* __restrict__ w,
                                             const float* __restrict__ y,
                                             u16* __restrict__ wmod) {
  const int oc = blockIdx.x, b = blockIdx.y;
  const int ic = threadIdx.x;               // 128 threads
  const float* wp = w + (oc * 128 + ic) * 27;
  float wv[27];
  float s = 0.f;
#pragma unroll
  for (int t = 0; t < 27; ++t) { wv[t] = wp[t]; s += wv[t] * wv[t]; }
  const float yv = y[b * 128 + ic];
  float v = yv * yv * s;
#pragma unroll
  for (int m = 1; m < 64; m <<= 1) v += __shfl_xor(v, m);
  __shared__ float part[2];
  const int lane = ic & 63, wid = ic >> 6;
  if (lane == 0) part[wid] = v;
  __syncthreads();
  const float demod = rsqrtf(part[0] + part[1] + 1e-8f);
  const float sc = yv * demod;
#pragma unroll
  for (int t = 0; t < 27; ++t)
    wmod[((b * 27 + t) * 128 + oc) * 128 + ic] = f2bf(wv[t] * sc);
}

// ---------------- kernel 2: zero only the halo of xt ----------------------
__global__ __launch_bounds__(128) void khalo(u16* __restrict__ xt) {
  const int zy = blockIdx.x, b = blockIdx.y;
  const int zz = zy / NP, yy = zy % NP;
  u16* row = xt + ((size_t)((b * NP + zz) * NP + yy) * NP) * 128;
  u32* wp = (u32*)row;                      // 34*128 u16 = 2176 u32
  if (zz == 0 || zz == NP - 1 || yy == 0 || yy == NP - 1) {
#pragma unroll
    for (int i = 0; i < 17; ++i) wp[i * 128 + threadIdx.x] = 0;
  } else {
    if (threadIdx.x < 64) wp[threadIdx.x] = 0;
    else ((u32*)(row + 33 * 128))[threadIdx.x - 64] = 0;
  }
}

// ---------------- kernel 3: f32 -> bf16 transpose-cast (interior) ----------
__global__ __launch_bounds__(256) void kcastx(const float* __restrict__ x,
                                              u16* __restrict__ xt) {
  const int yq = blockIdx.x, z = blockIdx.y, b = blockIdx.z;
  const int tid = threadIdx.x;
  __shared__ u16 t[32 * 132];               // [x][ic], stride 132 kills conflicts
  const float* xp = x + (size_t)b * 128 * 32768 + (z * 32 + yq) * 32;
#pragma unroll
  for (int p = 0; p < 16; ++p) {
    const int ic = p * 8 + (tid >> 5), xx = tid & 31;
    t[xx * 132 + ic] = f2bf(xp[(size_t)ic * 32768 + xx]);
  }
  __syncthreads();
  u16* xtb = xt + (((size_t)(b * NP + z + 1) * NP + (yq + 1)) * NP + 1) * 128;
#pragma unroll
  for (int p = 0; p < 4; ++p) {
    const int xx = p * 8 + (tid >> 5), icq = tid & 31;
    *(ushort4*)(xtb + (size_t)xx * 128 + icq * 4) = *(const ushort4*)&t[xx * 132 + icq * 4];
  }
}

// ---------------- kernel 4: barrier-free-interior pipelined conv ----------
// R11 structure, but only ONE barrier per K-step (A tri-buffer + seam-only B
// rewrite make intra-K-step barriers unnecessary). Waves drift within a
// K-step so ds_read and MFMA overlap across waves (m114). Compiler inserts
// fine-grained lgkmcnt for frag->MFMA deps.
__global__ __launch_bounds__(512, 2) void kconv(const u16* __restrict__ xt,
                                                const u16* __restrict__ wmod,
                                                float* __restrict__ out) {
  __shared__ __align__(16) u16 Bsm[40960];    // 80 KiB: 18x2176 + clamp pad
  __shared__ __align__(16) u16 Asm[3][8192];  // 3 x 16 KiB [oc 128][64 ic]
  const int tid = threadIdx.x;
  const int lane = tid & 63, wn = tid >> 6;   // 8 waves along n
  const int l15 = lane & 15, sgq = lane >> 4;
  const int bid = blockIdx.x;
  const int wgid = ((bid & 7) << 5) + (bid >> 3);   // XCD: all-z per (b,yt)
  const int b = wgid >> 6, yt = (wgid >> 5) & 1, z = wgid & 31;
  const int y0 = yt << 4;

  const u16* xb = xt + (size_t)b * (NP * NP * NP) * 128;
  const u16* wb = wmod + (size_t)b * 27 * 16384;

  f32x4 acc[8][4];
#pragma unroll
  for (int i = 0; i < 8; ++i)
#pragma unroll
    for (int j = 0; j < 4; ++j) acc[i][j] = (f32x4){0.f, 0.f, 0.f, 0.f};

  // A staging per-thread source base (1024 slots, 2 loads/thread)
  const int aoc = tid >> 3, aj = tid & 7;
  const u16* asrc = wb + (aoc << 7) + ((aj ^ (aoc & 7)) << 3);
  const int adst = tid << 3;                  // u16; +4096 for k=1

  // B fragment per-lane bases
  int sybase[4], xp0[4];
#pragma unroll
  for (int nf = 0; nf < 4; ++nf) {
    sybase[nf] = (((wn << 1) + (nf >> 1)) + 1) * 2176;
    xp0[nf] = ((nf & 1) << 4) + l15 + 1;
  }
  const int kswz0 = sgq ^ (l15 & 7);

  auto stageA1 = [&](int ks2, int k) {        // one load of A(ks2)
    const int g2 = ks2 / 9, j2 = ks2 - g2 * 9;
    const int tap = (g2 >> 1) * 9 + j2, hh = g2 & 1;
    gload_lds16(asrc + tap * 16384 + (hh << 6) + (k << 13),
                &Asm[ks2 % 3][adst + (k << 12)]);
  };
  auto stageB = [&](int g) {                  // 10 loads/thread, linear dest
    const int dz = (g >> 1) - 1, hh = g & 1;
    const int zrow = (z + 1 + dz) * NP + y0;
#pragma unroll
    for (int r = 0; r < 10; ++r) {
      int s = r * 512 + tid;
      const int dst = s << 3;                 // UNCLAMPED (pad absorbs tail)
      s = s < 4896 ? s : 4895;
      const int sy = s / 272;
      const int rem = s - sy * 272;
      const int xpos = rem >> 3, j = rem & 7;
      gload_lds16(xb + (size_t)((zrow + sy) * NP + xpos) * 128 + (hh << 6) +
                      ((j ^ (xpos & 7)) << 3),
                  &Bsm[dst]);
    }
  };
  auto ldAf = [&](bf16x8* af, int par, int mh, int kswz) {
    const u16* Ah = &Asm[par][0];
#pragma unroll
    for (int mm = 0; mm < 4; ++mm) {
      const int oc = (mh << 6) + (mm << 4) + l15;
      af[mm] = *(const bf16x8*)&Ah[(oc << 6) + (kswz << 3)];
    }
  };
  auto ldBv = [&](bf16x8* bv, int kk, int dy, int dx) {
#pragma unroll
    for (int nf = 0; nf < 4; ++nf) {
      const int xp = xp0[nf] + dx;
      const int off = sybase[nf] + dy * 2176 + (xp << 6) +
                      ((((kk << 2) + sgq) ^ (xp & 7)) << 3);
      bv[nf] = *(const bf16x8*)&Bsm[off];
    }
  };

  bf16x8 af0[4], af1[4], bv0[4], bv1[4];

#define MFMA16(MH, AF, BV)                                                 \
  { __builtin_amdgcn_s_setprio(1);                                         \
    _Pragma("unroll") for (int mm = 0; mm < 4; ++mm)                       \
      _Pragma("unroll") for (int nf = 0; nf < 4; ++nf)                     \
        acc[(MH) * 4 + mm][nf] = __builtin_amdgcn_mfma_f32_16x16x32_bf16(  \
            (AF)[mm], (BV)[nf], acc[(MH) * 4 + mm][nf], 0, 0, 0);          \
    __builtin_amdgcn_s_setprio(0); }

  // prologue: B(group0) + A(0) + A(1), full drain once
  stageB(0);
  stageA1(0, 0); stageA1(0, 1);
  stageA1(1, 0); stageA1(1, 1);
  WAITV(0); BAR();

  for (int g = 0; g < 6; ++g) {
    for (int j = 0; j < 9; ++j) {
      const int ks = g * 9 + j;
      const int par = ks % 3;
      const int dy = j / 3 - 1, dx = (j % 3) - 1;
      const int ks2 = (ks + 2 <= 53) ? ks + 2 : 53;
      // ---- barrier-free K-step interior (4 quarters) ----
      ldAf(af0, par, 0, kswz0);
      ldBv(bv0, 0, dy, dx);
      stageA1(ks2, 0);
      MFMA16(0, af0, bv0);
      ldAf(af1, par, 1, kswz0);
      stageA1(ks2, 1);
      MFMA16(1, af1, bv0);
      ldAf(af0, par, 0, kswz0 ^ 4);
      ldBv(bv1, 1, dy, dx);
      MFMA16(0, af0, bv1);
      ldAf(af1, par, 1, kswz0 ^ 4);
      MFMA16(1, af1, bv1);
      // ---- K-step boundary: the ONLY sync ----
      if (j < 8) {
        WAITV(2); BAR();            // drains A(ks+1); leaves A(ks+2) in flight
      } else if (g < 5) {
        BAR();                      // all reads of Bsm(group g) done
        stageB(g + 1);
        WAITV(0); BAR();            // B(g+1) + all A prefetches visible
      }
    }
  }

  // epilogue: C/D col=l15 (n), row=sgq*4+r (oc within 16)
#pragma unroll
  for (int m = 0; m < 8; ++m) {
    const int ocb = (m << 4) + (sgq << 2);
#pragma unroll
    for (int nf = 0; nf < 4; ++nf) {
      const int n = (wn << 6) + (nf << 4) + l15;
      const int yy = n >> 5, xx = n & 31;
      float* op = out + ((size_t)(b * 128 + ocb) << 15) + (z << 10) +
                  ((y0 + yy) << 5) + xx;
#pragma unroll
      for (int r = 0; r < 4; ++r) op[(size_t)r << 15] = acc[m][nf][r];
    }
  }
#undef MFMA16
}

extern "C" void kernel_launch(void* const* d_in, const int* in_sizes, int n_in,
                              void* d_out, int out_size, void* d_ws, size_t ws_size,
                              hipStream_t stream) {
  const float* x = (const float*)d_in[0];
  const float* y = (const float*)d_in[1];
  const float* w = (const float*)d_in[2];
  float* out = (float*)d_out;
  u16* xt = (u16*)d_ws;
  u16* wmod = (u16*)((char*)d_ws + XT_BYTES);

  hipLaunchKernelGGL(khalo, dim3(NP * NP, 4), dim3(128), 0, stream, xt);
  hipLaunchKernelGGL(kmodw, dim3(128, 4), dim3(128), 0, stream, w, y, wmod);
  hipLaunchKernelGGL(kcastx, dim3(32, 32, 4), dim3(256), 0, stream, x, xt);
  hipLaunchKernelGGL(kconv, dim3(256), dim3(512), 0, stream, xt, wmod, out);
}